// Round 14
// baseline (121.932 us; speedup 1.0000x reference)
//
#include <hip/hip_runtime.h>
#include <hip/hip_bf16.h>

#define BB 8
#define NN 2048
#define DD 128
#define TI 32     // i-rows per GEMM block (256 threads)
#define HP 132    // padded row stride for 128-wide LDS tiles
#define CH 32     // chunk length
#define NC (NN / CH)   // 64 chunks per batch
#define NO (NC + 1)    // 65 offset rows (incl. grand total)
#define NFIX (BB * NO) // 520 fix blocks inside mid kernel

__device__ __forceinline__ float relu(float x) { return x > 0.f ? x : 0.f; }

// ---------- Kernel 0: WT[d][e] = W[e][d] ----------
__global__ __launch_bounds__(256) void GraphAttentionalLayer_1168231104632_tr(
    const float* __restrict__ W, float* __restrict__ WT)
{
    const int g = blockIdx.x * 256 + threadIdx.x;
    const int d = g >> 7, e = g & 127;
    WT[g] = W[e * DD + d];
}

// ---------- Kernel 1: hw = h@W^T ; E=exp(si), F=exp(sj) ----------
// TI=32 rows/block, 256 threads, float4 LDS reads on BOTH operands
// (per 4-dd step: 8 x ds_read_b128 ~= 96 cyc vs 128 cyc of FMA -> VALU-bound).
__global__ __launch_bounds__(256) void GraphAttentionalLayer_1168231104632_kernel(
    const float* __restrict__ h,
    const float* __restrict__ WT,
    const float* __restrict__ a,
    float* __restrict__ hw,
    float* __restrict__ E,
    float* __restrict__ F)
{
    __shared__ float h_s[TI][HP];     // 16.9 KB
    __shared__ float wt_s[32][HP];    // 16.9 KB

    const int tid = threadIdx.x;
    const int t = tid & 127;
    const int hh = tid >> 7;          // 0/1
    const int tx = tid & 31, ty = tid >> 5;   // ty in 0..7
    const int b = blockIdx.x >> 6;
    const int i0 = (blockIdx.x & 63) * TI;
    const size_t base = ((size_t)b * NN + i0) * DD;

    for (int r = hh; r < TI; r += 2)
        h_s[r][t] = h[base + (size_t)r * DD + t];

    const int e0 = tx * 4, r0 = ty * 4;
    float acc[4][4];
#pragma unroll
    for (int i = 0; i < 4; i++)
#pragma unroll
        for (int j = 0; j < 4; j++) acc[i][j] = 0.f;

    for (int dc = 0; dc < DD; dc += 32) {
        __syncthreads();
        for (int rr = hh; rr < 32; rr += 2)
            wt_s[rr][t] = WT[(size_t)(dc + rr) * DD + t];
        __syncthreads();
#pragma unroll
        for (int dd = 0; dd < 32; dd += 4) {
            float wq[4][4], hq[4][4];
#pragma unroll
            for (int q = 0; q < 4; q++) {
                const float4 v = *reinterpret_cast<const float4*>(&wt_s[dd + q][e0]);
                wq[q][0] = v.x; wq[q][1] = v.y; wq[q][2] = v.z; wq[q][3] = v.w;
            }
#pragma unroll
            for (int r = 0; r < 4; r++) {
                const float4 v = *reinterpret_cast<const float4*>(&h_s[r0 + r][dc + dd]);
                hq[r][0] = v.x; hq[r][1] = v.y; hq[r][2] = v.z; hq[r][3] = v.w;
            }
#pragma unroll
            for (int r = 0; r < 4; r++)
#pragma unroll
                for (int q = 0; q < 4; q++) {
                    const float hv = hq[r][q];
#pragma unroll
                    for (int e = 0; e < 4; e++) acc[r][e] += hv * wq[q][e];
                }
        }
    }

#pragma unroll
    for (int r = 0; r < 4; r++) {
        float4 o = make_float4(acc[r][0], acc[r][1], acc[r][2], acc[r][3]);
        *reinterpret_cast<float4*>(&hw[base + (size_t)(r0 + r) * DD + e0]) = o;
    }

    const float4 aiv = *reinterpret_cast<const float4*>(&a[e0]);
    const float4 ajv = *reinterpret_cast<const float4*>(&a[DD + e0]);
    const float ai4[4] = {aiv.x, aiv.y, aiv.z, aiv.w};
    const float aj4[4] = {ajv.x, ajv.y, ajv.z, ajv.w};
#pragma unroll
    for (int r = 0; r < 4; r++) {
        float pi = 0.f, pj = 0.f;
#pragma unroll
        for (int e = 0; e < 4; e++) { pi += acc[r][e] * ai4[e]; pj += acc[r][e] * aj4[e]; }
#pragma unroll
        for (int off = 16; off > 0; off >>= 1) {
            pi += __shfl_down(pi, off, 32);
            pj += __shfl_down(pj, off, 32);
        }
        if (tx == 0) {
            const size_t row = (size_t)b * NN + i0 + r0 + r;
            E[row] = __expf(pi);
            F[row] = __expf(pj);
        }
    }
}

// ---------- Kernel 2: rank-sort, cooperative (r9 verbatim) ----------
__global__ __launch_bounds__(256) void GraphAttentionalLayer_1168231104632_rank(
    const float* __restrict__ F,
    float* __restrict__ Fsorted,
    int* __restrict__ perm)
{
    __shared__ float F_s[NN];
    __shared__ int   part[4][64];

    const int t = threadIdx.x;
    const int b = blockIdx.x >> 5;
    const int j0 = (blockIdx.x & 31) * 64;
    const size_t nb = (size_t)b * NN;

    for (int q = 0; q < NN / 256; q++)
        F_s[q * 256 + t] = F[nb + q * 256 + t];
    __syncthreads();

    const int tj = t & 63, ts = t >> 6;
    const int j = j0 + tj;
    const float fj = F_s[j];
    const int m0 = ts * (NN / 4);
    int cnt = 0;
#pragma unroll 8
    for (int mi = 0; mi < NN / 4; mi++) {
        const int m = m0 + mi;
        const float fm = F_s[m];
        cnt += (fm < fj) | ((fm == fj) & (m < j));
    }
    part[ts][tj] = cnt;
    __syncthreads();
    if (ts == 0) {
        const int r = part[0][tj] + part[1][tj] + part[2][tj] + part[3][tj];
        Fsorted[nb + r] = fj;
        perm[nb + r] = j;
    }
}

// ---------- Kernel 3: per-chunk sums only (Q arrays eliminated) ----------
__global__ __launch_bounds__(128) void GraphAttentionalLayer_1168231104632_csum(
    const float* __restrict__ hw,
    const float* __restrict__ Fsorted,
    const int* __restrict__ perm,
    float* __restrict__ C0,  float* __restrict__ C1)
{
    const int t = threadIdx.x;
    const int b = blockIdx.x / NC, c = blockIdx.x % NC;
    const size_t nb = (size_t)b * NN;
    const int m0 = c * CH;

    int   jv[CH];
    float Fv[CH];
#pragma unroll
    for (int mm = 0; mm < CH; mm++) jv[mm] = perm[nb + m0 + mm];
#pragma unroll
    for (int mm = 0; mm < CH; mm++) Fv[mm] = Fsorted[nb + m0 + mm];

    float hv[CH];
#pragma unroll
    for (int mm = 0; mm < CH; mm++)
        hv[mm] = hw[(nb + jv[mm]) * DD + t];

    float a0 = 0.f, a1 = 0.f;
#pragma unroll
    for (int mm = 0; mm < CH; mm++) {
        a0 += hv[mm];
        a1 += Fv[mm] * hv[mm];
    }
    C0[((size_t)b * NC + c) * DD + t] = a0;
    C1[((size_t)b * NC + c) * DD + t] = a1;
}

// ---------- Kernel 4 (mid): fix offsets + parallel LDS search (r13 verbatim) ----------
__global__ __launch_bounds__(256) void GraphAttentionalLayer_1168231104632_mid(
    const float* __restrict__ C0, const float* __restrict__ C1,
    const float* __restrict__ Fsorted, const float* __restrict__ E,
    float* __restrict__ O0, float* __restrict__ O1,
    int* __restrict__ kk,  float* __restrict__ zinv)
{
    __shared__ float fs_s[NN];      // 8 KB
    __shared__ float cf_s[NC];
    __shared__ float of_s[NO];

    const int tid = threadIdx.x;

    if (blockIdx.x < NFIX) {
        const int b = blockIdx.x / NO, c = blockIdx.x % NO;
        const int d = tid & 127;
        const float* C = (tid < 128) ? C0 : C1;
        float*       O = (tid < 128) ? O0 : O1;
        float o = 0.f;
        int c2 = 0;
        for (; c2 + 16 <= c; c2 += 16) {
            float v[16];
#pragma unroll
            for (int q = 0; q < 16; q++)
                v[q] = C[((size_t)b * NC + c2 + q) * DD + d];
#pragma unroll
            for (int q = 0; q < 16; q++) o += v[q];
        }
        for (; c2 < c; c2++)
            o += C[((size_t)b * NC + c2) * DD + d];
        O[((size_t)b * NO + c) * DD + d] = o;
        return;
    }

    const int sb = blockIdx.x - NFIX;
    const int b = sb >> 3;
    const int i0 = (sb & 7) * 256;
    const size_t nb = (size_t)b * NN;

    for (int q = 0; q < NN / 256; q++)
        fs_s[q * 256 + tid] = Fsorted[nb + q * 256 + tid];
    __syncthreads();

    if (tid < NC) {
        float p = 0.f;
        const int m0 = tid * CH;
#pragma unroll
        for (int mm = 0; mm < CH; mm++) p += fs_s[m0 + mm];
        cf_s[tid] = p;
    }
    __syncthreads();
    if (tid < NO) {
        float p = 0.f;
        for (int c2 = 0; c2 < tid; c2++) p += cf_s[c2];
        of_s[tid] = p;
    }
    __syncthreads();

    const int row = (int)nb + i0 + tid;
    const float Ei = E[row];
    const float thr = 1.0f / Ei;
    int lo = 0, hi = NN;
    while (lo < hi) {
        const int mid = (lo + hi) >> 1;
        if (fs_s[mid] < thr) lo = mid + 1; else hi = mid;
    }
    float fpl = 0.f;
    for (int m = (lo >> 5) << 5; m < lo; m++) fpl += fs_s[m];
    const float TF = of_s[NC];
    const float Pk = of_s[lo >> 5] + fpl;
    const float z = Ei * (TF - Pk) + (float)lo;
    kk[row] = lo;
    zinv[row] = 1.0f / z;
}

// ---------- Kernel 5: output — in-block remainder sum (no Q arrays) ----------
// 256 threads; rows split 2-way (group g = tid>>7), LDS reduce; XCD swizzle.
__global__ __launch_bounds__(256) void GraphAttentionalLayer_1168231104632_out(
    const float* __restrict__ hw,
    const int* __restrict__ perm, const float* __restrict__ Fsorted,
    const float* __restrict__ O0, const float* __restrict__ O1,
    const int* __restrict__ kk,   const float* __restrict__ zinv,
    const float* __restrict__ E,  float* __restrict__ out)
{
    __shared__ int   pm_s[CH];
    __shared__ float fj_s[CH];
    __shared__ float q_s[2][2][DD];

    const int tid = threadIdx.x;
    const int t = tid & 127;
    const int g = tid >> 7;
    const int blk = blockIdx.x;
    const int row = ((blk & 7) << 11) | (blk >> 3);   // batch -> XCD locality
    const int b = row >> 11;
    const size_t nb = (size_t)b * NN;

    const int k = kk[row];          // uniform
    const int c = k >> 5;
    const int rem = k & 31;

    if (tid < CH && rem) {
        pm_s[tid] = perm[nb + c * CH + tid];
        fj_s[tid] = Fsorted[nb + c * CH + tid];
    }
    __syncthreads();

    float q0 = 0.f, q1 = 0.f;
#pragma unroll 4
    for (int m = g; m < rem; m += 2) {
        const int j = pm_s[m];                    // uniform (LDS broadcast)
        const float hv = hw[(nb + j) * DD + t];   // coalesced 512B, L2-hot
        q0 += hv;
        q1 += fj_s[m] * hv;
    }
    q_s[0][g][t] = q0;
    q_s[1][g][t] = q1;
    __syncthreads();

    if (tid < DD) {
        const float Ev = E[row];
        const float zv = zinv[row];
        const float T1 = O1[((size_t)b * NO + NC) * DD + t];
        const float Q0 = O0[((size_t)b * NO + c) * DD + t] + q_s[0][0][t] + q_s[0][1][t];
        const float Q1 = O1[((size_t)b * NO + c) * DD + t] + q_s[1][0][t] + q_s[1][1][t];
        const float num = Ev * (T1 - Q1) + Q0;
        out[(size_t)row * DD + t] = relu(num * zv);
    }
}

extern "C" __attribute__((visibility("default")))
void kernel_launch(void* const* d_in, const int* in_sizes, int n_in,
                   void* d_out, int out_size, void* d_ws, size_t ws_size,
                   hipStream_t stream) {
    const float* h = nullptr; const float* W = nullptr; const float* a = nullptr;
    for (int i = 0; i < n_in; i++) {
        if (in_sizes[i] == BB * NN * DD)      h = (const float*)d_in[i];
        else if (in_sizes[i] == DD * DD)      W = (const float*)d_in[i];
        else if (in_sizes[i] == 2 * DD)       a = (const float*)d_in[i];
    }
    if (!h) h = (const float*)d_in[0];
    if (!W) W = (const float*)d_in[1];
    if (!a) a = (const float*)d_in[2];

    float* out = (float*)d_out;
    float* ws = (float*)d_ws;

    float* WT   = ws;                              // 16,384
    float* hw   = WT + DD * DD;                    // 2,097,152
    float* E    = hw + (size_t)BB * NN * DD;       // 16,384
    float* F    = E + BB * NN;                     // 16,384
    float* Fs   = F + BB * NN;                     // 16,384
    float* zinv = Fs + BB * NN;                    // 16,384
    int*   perm = (int*)(zinv + BB * NN);          // 16,384
    int*   kk   = perm + BB * NN;                  // 16,384
    float* C0   = (float*)(kk + BB * NN);          // 65,536
    float* C1   = C0 + BB * NC * DD;               // 65,536
    float* O0   = C1 + BB * NC * DD;               // 66,560
    float* O1   = O0 + BB * NO * DD;               // 66,560
    const size_t need = (size_t)((O1 + BB * NO * DD) - ws) * sizeof(float); // ~9.7 MB

    if (ws_size < need || d_ws == nullptr) {
        hipMemsetAsync(d_out, 0x42, (size_t)out_size * sizeof(float), stream);
        return;
    }

    GraphAttentionalLayer_1168231104632_tr<<<(DD * DD) / 256, 256, 0, stream>>>(W, WT);
    GraphAttentionalLayer_1168231104632_kernel<<<BB * (NN / TI), 256, 0, stream>>>(h, WT, a, hw, E, F);
    GraphAttentionalLayer_1168231104632_rank<<<BB * 32, 256, 0, stream>>>(F, Fs, perm);
    GraphAttentionalLayer_1168231104632_csum<<<BB * NC, 128, 0, stream>>>(hw, Fs, perm, C0, C1);
    GraphAttentionalLayer_1168231104632_mid<<<NFIX + BB * 8, 256, 0, stream>>>(C0, C1, Fs, E, O0, O1, kk, zinv);
    GraphAttentionalLayer_1168231104632_out<<<BB * NN, 256, 0, stream>>>(hw, perm, Fs, O0, O1, kk, zinv, E, out);
}